// Round 15
// baseline (137.392 us; speedup 1.0000x reference)
//
#include <hip/hip_runtime.h>
#include <hip/hip_bf16.h>

// KroneckerProjection: out = X @ kron(A,B), factored.
//   T[m][j][k] = sum_i x[m][i*16+k]*A[i][j];  out[m][j*512+l] = sum_k T*B[k][l]
// r15 = phase-split experiment, FIRST REAL RUN (r11-r13 all died on a dead
// container; r14 confirmed the pool rotated and reproduced the r6 champion
// at 128us). TWO-KERNEL PHASE SPLIT turns r6's mixed read/write stream into
// two pure streams (pure streams measured faster: fill 6.6-6.8 TB/s vs our
// mixed 5.3):
//   K1: x (128MB, NT loads, 64B-atom aligned) -> step-1 fp32 -> T (16MB,
//       CACHED stores so T stays L2/L3-resident for K2).
//   K2: T from cache -> bf16 MFMA -> per-wave LDS transpose -> 512B-contiguous
//       NT stores (byte-identical to r6's proven store path). ~pure-write.
// Fallback: if ws_size < 16.8MB, run r6 verbatim (champion, 127us).

#define DIN   2048
#define DOUT  8192
#define TS    268      // T_lds row stride (dwords): 16B-aligned, bank-spread
#define TRS   132      // transpose tile row stride (dwords): 16B-aligned

typedef __attribute__((ext_vector_type(8))) short bf16x8;
typedef __attribute__((ext_vector_type(4))) float f32x4;

__device__ __forceinline__ short f2bf(float f) {
    __hip_bfloat16 h = __float2bfloat16(f);   // RNE
    short s;
    __builtin_memcpy(&s, &h, 2);
    return s;
}

// ---------------- K1: T = x4 @ A  (read-dominated pure stream) -------------
__global__ __launch_bounds__(256)
void kron_t_kernel(const float* __restrict__ x,
                   const float* __restrict__ A,
                   float* __restrict__ Tg)
{
    const int t    = threadIdx.x;
    const int w    = t >> 6;
    const int lane = t & 63;
    const int row0 = blockIdx.x * 16;
    const int r = lane >> 4, k = lane & 15;

    float T[16];
#pragma unroll
    for (int j = 0; j < 16; ++j) T[j] = 0.f;

    const float* xr = x + (size_t)(row0 + 4 * w + r) * DIN + k;
#pragma unroll 8
    for (int i = 0; i < 128; ++i) {
        const float xv = __builtin_nontemporal_load(xr + i * 16); // 64B atoms
        const float* Ar = A + i * 16;         // uniform -> s_load
#pragma unroll
        for (int j = 0; j < 16; ++j) T[j] = fmaf(xv, Ar[j], T[j]);
    }
    // cached stores: T (16MB total) stays L2/L3-resident for K2
    float* To = Tg + (size_t)(row0 + 4 * w + r) * 256 + k;
#pragma unroll
    for (int j = 0; j < 16; ++j) To[j * 16] = T[j];
}

// ---------------- K2: out = T @ B  (write-dominated pure stream) -----------
__global__ __launch_bounds__(256, 3)
void kron_out_kernel(const float* __restrict__ Tg,
                     const float* __restrict__ B,
                     float* __restrict__ out)
{
    __shared__ __align__(16) float T_lds[16 * TS];        // 17.2 KiB
    __shared__ __align__(16) float trans[4][16 * TRS];    // 33.8 KiB

    const int t    = threadIdx.x;
    const int w    = t >> 6;
    const int lane = t & 63;
    const int row0 = blockIdx.x * 16;

    // stage T tile (16 rows x 256) -> padded LDS, float4 coalesced
    {
        const float4* Tg4 = (const float4*)(Tg + (size_t)row0 * 256);
#pragma unroll
        for (int it = 0; it < 4; ++it) {
            const int idx = it * 256 + t;     // 0..1023 float4s
            const int row = idx >> 6;         // 64 float4 per row
            const int c4  = idx & 63;
            *(float4*)(T_lds + row * TS + c4 * 4) = Tg4[idx];
        }
    }

    // B-frags (verified): elem e = B[k=q*8+e][w*128 + c*16 + n]; q>=2 zero
    const int q = lane >> 4;
    const int n = lane & 15;
    bf16x8 bfrag[8];
#pragma unroll
    for (int c = 0; c < 8; ++c) {
        bf16x8 f = (bf16x8)0;
        if (q < 2) {
            const float* Bp = B + (size_t)(q * 8) * 512 + w * 128 + c * 16 + n;
#pragma unroll
            for (int e = 0; e < 8; ++e) f[e] = f2bf(Bp[(size_t)e * 512]);
        }
        bfrag[c] = f;
    }

    __syncthreads();

    float* tw = trans[w];
    const int rrow = (lane >> 5);
    const int c4   = (lane & 31) * 4;

#pragma unroll 2
    for (int j = 0; j < 16; ++j) {
        // afrag on demand (verified layout): elem e = U[m=n][k=q*8+e]
        bf16x8 af = (bf16x8)0;
        if (q < 2) {
            const float* Tp = T_lds + n * TS + j * 16 + q * 8;
            float4 t0 = *(const float4*)(Tp);
            float4 t1 = *(const float4*)(Tp + 4);
            af[0] = f2bf(t0.x); af[1] = f2bf(t0.y);
            af[2] = f2bf(t0.z); af[3] = f2bf(t0.w);
            af[4] = f2bf(t1.x); af[5] = f2bf(t1.y);
            af[6] = f2bf(t1.z); af[7] = f2bf(t1.w);
        }

        // MFMA; D(lane(q,n), reg p) = out[row=q*4+p][col=c*16+n] -> LDS transpose
#pragma unroll
        for (int c = 0; c < 8; ++c) {
            f32x4 d = {0.f, 0.f, 0.f, 0.f};
            d = __builtin_amdgcn_mfma_f32_16x16x32_bf16(af, bfrag[c], d, 0, 0, 0);
            float* tp = tw + c * 16 + n;
            tp[(q * 4 + 0) * TRS] = d[0];
            tp[(q * 4 + 1) * TRS] = d[1];
            tp[(q * 4 + 2) * TRS] = d[2];
            tp[(q * 4 + 3) * TRS] = d[3];
        }

        // read back coalesced; NT stores: 8 instrs x 512B contiguous (r6 path)
        float* ob = out + (size_t)row0 * DOUT + j * 512 + w * 128 + c4;
#pragma unroll
        for (int rp = 0; rp < 8; ++rp) {
            const int row = 2 * rp + rrow;
            f32x4 v = *(const f32x4*)(tw + row * TRS + c4);
            __builtin_nontemporal_store(v, (f32x4*)(ob + (size_t)row * DOUT));
        }
    }
}

// ---------------- Fallback: r6 champion verbatim (single kernel) -----------
__global__ __launch_bounds__(256, 3)
void kron_mfma3_kernel(const float* __restrict__ x,
                       const float* __restrict__ A,
                       const float* __restrict__ B,
                       float* __restrict__ out)
{
    __shared__ __align__(16) float T_lds[16 * TS];
    __shared__ __align__(16) float trans[4][16 * TRS];

    const int t    = threadIdx.x;
    const int w    = t >> 6;
    const int lane = t & 63;
    const int row0 = blockIdx.x * 16;

    const int r = lane >> 4, k = lane & 15;
    {
        float T[16];
#pragma unroll
        for (int j = 0; j < 16; ++j) T[j] = 0.f;
        const float* xr = x + (size_t)(row0 + 4 * w + r) * DIN + k;
#pragma unroll 8
        for (int i = 0; i < 128; ++i) {
            const float xv = xr[i * 16];
            const float* Ar = A + i * 16;
#pragma unroll
            for (int j = 0; j < 16; ++j) T[j] = fmaf(xv, Ar[j], T[j]);
        }
        float* Tm = T_lds + (4 * w + r) * TS + k;
#pragma unroll
        for (int j = 0; j < 16; ++j) Tm[j * 16] = T[j];
    }

    const int q = lane >> 4;
    const int n = lane & 15;
    bf16x8 bfrag[8];
#pragma unroll
    for (int c = 0; c < 8; ++c) {
        bf16x8 f = (bf16x8)0;
        if (q < 2) {
            const float* Bp = B + (size_t)(q * 8) * 512 + w * 128 + c * 16 + n;
#pragma unroll
            for (int e = 0; e < 8; ++e) f[e] = f2bf(Bp[(size_t)e * 512]);
        }
        bfrag[c] = f;
    }

    __syncthreads();

    float* tw = trans[w];
#pragma unroll 2
    for (int j = 0; j < 16; ++j) {
        bf16x8 af = (bf16x8)0;
        if (q < 2) {
            const float* Tp = T_lds + n * TS + j * 16 + q * 8;
            float4 t0 = *(const float4*)(Tp);
            float4 t1 = *(const float4*)(Tp + 4);
            af[0] = f2bf(t0.x); af[1] = f2bf(t0.y);
            af[2] = f2bf(t0.z); af[3] = f2bf(t0.w);
            af[4] = f2bf(t1.x); af[5] = f2bf(t1.y);
            af[6] = f2bf(t1.z); af[7] = f2bf(t1.w);
        }
#pragma unroll
        for (int c = 0; c < 8; ++c) {
            f32x4 d = {0.f, 0.f, 0.f, 0.f};
            d = __builtin_amdgcn_mfma_f32_16x16x32_bf16(af, bfrag[c], d, 0, 0, 0);
            float* tp = tw + c * 16 + n;
            tp[(q * 4 + 0) * TRS] = d[0];
            tp[(q * 4 + 1) * TRS] = d[1];
            tp[(q * 4 + 2) * TRS] = d[2];
            tp[(q * 4 + 3) * TRS] = d[3];
        }
        const int rrow = (lane >> 5);
        const int c4   = (lane & 31) * 4;
        float* ob = out + (size_t)row0 * DOUT + j * 512 + w * 128 + c4;
#pragma unroll
        for (int rp = 0; rp < 8; ++rp) {
            const int row = 2 * rp + rrow;
            f32x4 v = *(const f32x4*)(tw + row * TRS + c4);
            __builtin_nontemporal_store(v, (f32x4*)(ob + (size_t)row * DOUT));
        }
    }
}

extern "C" void kernel_launch(void* const* d_in, const int* in_sizes, int n_in,
                              void* d_out, int out_size, void* d_ws, size_t ws_size,
                              hipStream_t stream) {
    const float* x = (const float*)d_in[0];
    const float* A = (const float*)d_in[1];
    const float* B = (const float*)d_in[2];
    float* out = (float*)d_out;

    const int nrows = in_sizes[0] / DIN;                  // 16384
    const int grid  = nrows / 16;                         // 1024 blocks
    const size_t t_bytes = (size_t)nrows * 256 * sizeof(float);  // 16.78 MB

    if (ws_size >= t_bytes) {
        float* Tg = (float*)d_ws;
        kron_t_kernel<<<dim3(grid), dim3(256), 0, stream>>>(x, A, Tg);
        kron_out_kernel<<<dim3(grid), dim3(256), 0, stream>>>(Tg, B, out);
    } else {
        kron_mfma3_kernel<<<dim3(grid), dim3(256), 0, stream>>>(x, A, B, out);
    }
}

// Round 16
// 131.017 us; speedup vs baseline: 1.0487x; 1.0487x over previous
//
#include <hip/hip_runtime.h>
#include <hip/hip_bf16.h>

// KroneckerProjection: out = X @ kron(A,B), factored.
//   Step 1 (fp32 VALU, verified): T[m][j][k] = sum_i x[m][i*16+k]*A[i][j]
//   Step 2 (bf16 MFMA, verified):  out[m][j*512+l] = sum_k T[m][j][k]*B[k][l]
// r16 = FINAL: r6 champion verbatim (126.7us r6, 128.0us r14 — reproducible;
// absmax 2.0 << 7.48). The phase-split experiment (r15) measured 137.4us,
// killing the last open theory (mixed-stream turnaround penalty). Ladder:
//   141 naive-LDS -> 146/142 readlane -> 162 MFMA-scatter -> 141.7 MFMA+
//   LDS-transpose -> 126.7 +NT stores -> (occupancy variants 138/132,
//   NT-scatter 223, phase-split 137 all worse).
// Structure: per-block 16 rows, 4 waves; step-1 fp32 in registers -> padded
// T_lds; bf16 MFMA (K=16 zero-padded in 16x16x32); D transposed through
// per-wave LDS tile; 512B-contiguous NONTEMPORAL float4 stores (write-around
// — the decisive +15us lever; NT requires full-line contiguity, r10 proved
// NT-scatter is catastrophic). 5.3 TB/s effective on 671 MB traffic.

#define DIN   2048
#define DOUT  8192
#define TS    268      // T_lds row stride (dwords): 16B-aligned, bank-spread
#define TRS   132      // transpose tile row stride (dwords): 16B-aligned

typedef __attribute__((ext_vector_type(8))) short bf16x8;
typedef __attribute__((ext_vector_type(4))) float f32x4;

__device__ __forceinline__ short f2bf(float f) {
    __hip_bfloat16 h = __float2bfloat16(f);   // RNE
    short s;
    __builtin_memcpy(&s, &h, 2);
    return s;
}

__global__ __launch_bounds__(256, 3)
void kron_mfma3_kernel(const float* __restrict__ x,
                       const float* __restrict__ A,
                       const float* __restrict__ B,
                       float* __restrict__ out)
{
    __shared__ __align__(16) float T_lds[16 * TS];        // 17.2 KiB
    __shared__ __align__(16) float trans[4][16 * TRS];    // 33.8 KiB

    const int t    = threadIdx.x;
    const int w    = t >> 6;                  // wave 0..3
    const int lane = t & 63;
    const int row0 = blockIdx.x * 16;

    // ---- Step 1: rows row0+4w..+3, lane=(r,k) — verified fp32 path
    const int r = lane >> 4, k = lane & 15;
    {
        float T[16];
#pragma unroll
        for (int j = 0; j < 16; ++j) T[j] = 0.f;

        const float* xr = x + (size_t)(row0 + 4 * w + r) * DIN + k;
#pragma unroll 8
        for (int i = 0; i < 128; ++i) {
            const float xv = xr[i * 16];      // coalesced 64B segments
            const float* Ar = A + i * 16;     // uniform -> s_load
#pragma unroll
            for (int j = 0; j < 16; ++j) T[j] = fmaf(xv, Ar[j], T[j]);
        }
        float* Tm = T_lds + (4 * w + r) * TS + k;
#pragma unroll
        for (int j = 0; j < 16; ++j) Tm[j * 16] = T[j];
    }

    // ---- B-frags (verified): elem e = B[k=q*8+e][w*128 + c*16 + n]; q>=2 zero
    const int q = lane >> 4;
    const int n = lane & 15;
    bf16x8 bfrag[8];
#pragma unroll
    for (int c = 0; c < 8; ++c) {
        bf16x8 f = (bf16x8)0;
        if (q < 2) {
            const float* Bp = B + (size_t)(q * 8) * 512 + w * 128 + c * 16 + n;
#pragma unroll
            for (int e = 0; e < 8; ++e) f[e] = f2bf(Bp[(size_t)e * 512]);
        }
        bfrag[c] = f;
    }

    __syncthreads();   // all T rows visible to all waves

    float* tw = trans[w];

    // ---- Step 2 main loop over j
#pragma unroll 2
    for (int j = 0; j < 16; ++j) {
        // afrag on demand (verified layout): elem e = U[m=n][k=q*8+e]; q>=2 zero
        bf16x8 af = (bf16x8)0;
        if (q < 2) {
            const float* Tp = T_lds + n * TS + j * 16 + q * 8;
            float4 t0 = *(const float4*)(Tp);
            float4 t1 = *(const float4*)(Tp + 4);
            af[0] = f2bf(t0.x); af[1] = f2bf(t0.y);
            af[2] = f2bf(t0.z); af[3] = f2bf(t0.w);
            af[4] = f2bf(t1.x); af[5] = f2bf(t1.y);
            af[6] = f2bf(t1.z); af[7] = f2bf(t1.w);
        }

        // MFMA per 16-col chunk; D(lane(q,n), reg p) = out[row=q*4+p][col=c*16+n]
        // -> write transposed into LDS tile (2-way write banks = free)
#pragma unroll
        for (int c = 0; c < 8; ++c) {
            f32x4 d = {0.f, 0.f, 0.f, 0.f};
            d = __builtin_amdgcn_mfma_f32_16x16x32_bf16(af, bfrag[c], d, 0, 0, 0);
            float* tp = tw + c * 16 + n;
            tp[(q * 4 + 0) * TRS] = d[0];
            tp[(q * 4 + 1) * TRS] = d[1];
            tp[(q * 4 + 2) * TRS] = d[2];
            tp[(q * 4 + 3) * TRS] = d[3];
        }

        // read back coalesced; NONTEMPORAL stores: 512B contiguous per instr
        const int rrow = (lane >> 5);         // 0/1: row within pair
        const int c4   = (lane & 31) * 4;     // col offset within 128-col chunk
        float* ob = out + (size_t)row0 * DOUT + j * 512 + w * 128 + c4;
#pragma unroll
        for (int rp = 0; rp < 8; ++rp) {
            const int row = 2 * rp + rrow;
            f32x4 v = *(const f32x4*)(tw + row * TRS + c4);
            __builtin_nontemporal_store(v, (f32x4*)(ob + (size_t)row * DOUT));
        }
    }
}

extern "C" void kernel_launch(void* const* d_in, const int* in_sizes, int n_in,
                              void* d_out, int out_size, void* d_ws, size_t ws_size,
                              hipStream_t stream) {
    const float* x = (const float*)d_in[0];
    const float* A = (const float*)d_in[1];
    const float* B = (const float*)d_in[2];
    float* out = (float*)d_out;

    const int nrows = in_sizes[0] / DIN;      // 16384
    const int grid  = nrows / 16;             // 1024 blocks, 16 rows each

    kron_mfma3_kernel<<<dim3(grid), dim3(256), 0, stream>>>(x, A, B, out);
}